// Round 5
// baseline (148.251 us; speedup 1.0000x reference)
//
#include <hip/hip_runtime.h>

#define TT 8192
#define DD 64
#define MODS 4
#define NCH 256
#define CH  32    // TT / NCH
#define NG  32    // chunk groups (8 chunks each)

typedef __attribute__((ext_vector_type(8))) short bf16x8;
typedef __attribute__((ext_vector_type(4))) float f32x4;

// round-to-nearest-even fp32 -> bf16 bits
__device__ __forceinline__ unsigned f2bf1(float x) {
    unsigned u = __float_as_uint(x);
    return (u + 0x7FFFu + ((u >> 16) & 1u)) >> 16;
}
__device__ __forceinline__ unsigned packbf(float a, float b) {
    return f2bf1(a) | (f2bf1(b) << 16);
}

// stage one fp32 W layer [d][c] -> LDS bf16 W^T [c][d] (pitch 72 shorts).
// 256 threads: c = t&63, dp0 = t>>6. Coalesced global dword loads.
__device__ __forceinline__ void stage_w(const float* __restrict__ Wl,
                                        unsigned short* wb, int c, int dp0)
{
    #pragma unroll
    for (int it = 0; it < 8; ++it) {
        int dp = dp0 + 4 * it;                    // 0..31 (pair of d's)
        float w0 = Wl[(2 * dp)     * DD + c];
        float w1 = Wl[(2 * dp + 1) * DD + c];
        *(unsigned*)&wb[c * 72 + 2 * dp] = packbf(w0, w1);
    }
}

// ---------------------------------------------------------------------------
// Kernel 1: the 5 MLPs via bf16 MFMA, y^T = W^T x^T per layer.
// grid = (TT/64, 5), block 256 = 4 waves; wave owns 16 x-rows.
//   W staged ONCE PER BLOCK into LDS (bf16, double-buffered) -> W L1 traffic
//   and pack VALU divided by 4 vs per-wave direct loads (round-4 regression).
//   A-frag = ds_read_b128 from wbuf; B-frag = x rows from xbuf (per-wave,
//   barrier-free). C layout (m89-verified): col(lane&15)=row, quad*4+reg=col.
// ---------------------------------------------------------------------------
__global__ __launch_bounds__(256)
void mlp_kernel(const float* __restrict__ X,
                const float* __restrict__ wq_w, const float* __restrict__ wq_b,
                const float* __restrict__ wk_w, const float* __restrict__ wk_b,
                float* __restrict__ Q, float* __restrict__ Kout)
{
    __shared__ unsigned short xbuf[4][16][72];   //  9,216 B
    __shared__ unsigned short wbuf[2][64][72];   // 18,432 B

    const int job = blockIdx.y;
    const float *xin, *Wj, *Bias;
    float* out;
    if (job == 0) { xin = X; Wj = wq_w; Bias = wq_b; out = Q; }
    else {
        const int m = job - 1;
        xin  = X    + (size_t)m * TT * DD;
        Wj   = wk_w + (size_t)m * 3 * DD * DD;
        Bias = wk_b + (size_t)m * 3 * DD;
        out  = Kout + (size_t)m * TT * DD;
    }

    const int t    = threadIdx.x;
    const int wv   = t >> 6;
    const int lane = t & 63;
    const int quad = lane >> 4;
    const int l15  = lane & 15;
    const int row0 = blockIdx.x * 64 + wv * 16;   // this wave's 16 rows
    unsigned short* xb = &xbuf[wv][0][0];         // [16][72]
    const int wc = t & 63, wdp0 = t >> 6;         // staging roles

    // ---- stage this wave's 16x64 fp32 rows as bf16 into LDS ----
    {
        const float4* src = (const float4*)(xin + (size_t)row0 * DD);
        #pragma unroll
        for (int k = 0; k < 4; ++k) {
            int f = lane + 64 * k;                // float4 idx 0..255
            int r = f >> 4, c4 = (f & 15) << 2;   // row, col
            float4 v = src[f];
            uint2 p = make_uint2(packbf(v.x, v.y), packbf(v.z, v.w));
            *(uint2*)&xb[r * 72 + c4] = p;
        }
    }

    stage_w(Wj, &wbuf[0][0][0], wc, wdp0);        // layer 0 weights

    #pragma unroll
    for (int l = 0; l < 3; ++l) {
        __syncthreads();                          // wbuf[l&1] staged; prior reads done
        const unsigned short* wb = &wbuf[l & 1][0][0];
        if (l < 2)                                // prefetch next layer into alt slot
            stage_w(Wj + (size_t)(l + 1) * DD * DD, &wbuf[(l + 1) & 1][0][0], wc, wdp0);

        const float* Bl = Bias + l * DD;
        f32x4 acc[4];
        #pragma unroll
        for (int mt = 0; mt < 4; ++mt) {          // acc init = bias (C operand)
            float4 b4 = *(const float4*)(Bl + 16 * mt + quad * 4);
            acc[mt][0] = b4.x; acc[mt][1] = b4.y; acc[mt][2] = b4.z; acc[mt][3] = b4.w;
        }

        bf16x8 xf[2];                             // B-frags: x[r=l15][k=quad*8+j+32kt]
        #pragma unroll
        for (int kt = 0; kt < 2; ++kt)
            xf[kt] = *(const bf16x8*)&xb[l15 * 72 + quad * 8 + kt * 32];

        #pragma unroll
        for (int mt = 0; mt < 4; ++mt) {
            #pragma unroll
            for (int kt = 0; kt < 2; ++kt) {
                bf16x8 wf = *(const bf16x8*)&wb[(16 * mt + l15) * 72 + quad * 8 + kt * 32];
                acc[mt] = __builtin_amdgcn_mfma_f32_16x16x32_bf16(wf, xf[kt], acc[mt], 0, 0, 0);
            }
        }

        if (l < 2) {                              // relu + pack + writeback (own rows)
            #pragma unroll
            for (int mt = 0; mt < 4; ++mt) {
                float r0 = fmaxf(acc[mt][0], 0.f), r1 = fmaxf(acc[mt][1], 0.f);
                float r2 = fmaxf(acc[mt][2], 0.f), r3 = fmaxf(acc[mt][3], 0.f);
                uint2 p = make_uint2(packbf(r0, r1), packbf(r2, r3));
                *(uint2*)&xb[l15 * 72 + 16 * mt + quad * 4] = p;
            }
        } else {                                  // final: store fp32
            #pragma unroll
            for (int mt = 0; mt < 4; ++mt) {
                float4 v = make_float4(acc[mt][0], acc[mt][1], acc[mt][2], acc[mt][3]);
                *(float4*)(out + (size_t)(row0 + l15) * DD + 16 * mt + quad * 4) = v;
            }
        }
    }
}

// ---------------------------------------------------------------------------
// Kernel 2: per-chunk partial sums of K[t,d]*V[t,e], CH=32 rows/chunk.
// grid = (NCH, MODS) = 1024 blocks, block 128 (thread = e*64+d). Coalesced.
// ---------------------------------------------------------------------------
__global__ __launch_bounds__(128)
void scan_partial(const float* __restrict__ Kin, const float* __restrict__ X,
                  float* __restrict__ Ctot)
{
    const int m = blockIdx.y, ch = blockIdx.x;
    const int tid = threadIdx.x;
    const int d = tid & 63, e = tid >> 6;
    const float* Kb = Kin + ((size_t)m * TT + (size_t)ch * CH) * DD;
    const float* Vb = X   + ((size_t)m * TT + (size_t)ch * CH) * DD;
    float acc = 0.f;
    #pragma unroll 8
    for (int tt = 0; tt < CH; ++tt)
        acc = fmaf(Kb[tt * DD + d], Vb[tt * DD + e], acc);
    Ctot[((size_t)m * NCH + ch) * 128 + tid] = acc;
}

// ---------------------------------------------------------------------------
// Kernel 3: exclusive prefix over 32 groups of 8 chunks.
// grid = MODS, block 256 (two halves of 128 threads each scan 16 groups;
// LDS splice fixes up the upper half). ~128 pipelined loads per thread.
// ---------------------------------------------------------------------------
__global__ __launch_bounds__(256)
void g2_prefix(const float* __restrict__ Ctot, float* __restrict__ Pre2)
{
    __shared__ float pp[NG][128];                 // 16 KB, inclusive half-prefixes
    const int m = blockIdx.x;
    const int sub = threadIdx.x >> 7, t = threadIdx.x & 127;
    const int g0 = sub * 16;
    float acc = 0.f;
    for (int g = g0; g < g0 + 16; ++g) {
        float s = 0.f;
        #pragma unroll
        for (int i = 0; i < 8; ++i)
            s += Ctot[(size_t)(m * NCH + g * 8 + i) * 128 + t];
        acc += s;
        pp[g][t] = acc;
    }
    __syncthreads();
    for (int g = g0; g < g0 + 16; ++g) {
        float e = (g == 0) ? 0.f
                : (g <= 16) ? pp[g - 1][t]
                            : pp[15][t] + pp[g - 1][t];
        Pre2[(size_t)(m * NG + g) * 128 + t] = e;
    }
}

// ---------------------------------------------------------------------------
// Kernel 4: gather. ONE WAVE PER (query, modality): 8192 blocks x 4 waves
// (full occupancy -> 4x latency hiding vs round 4). Ballot k-ary search:
// 3 dependent 64-probe rounds (8192 -> 128 -> 2 -> exact) instead of 13
// serial binary steps. XCD swizzle keeps each XCD on a contiguous t-range.
// Base = Pre2[group] + <=7 Ctot rows + <=32-row recompute; LDS combine.
// ---------------------------------------------------------------------------
__global__ __launch_bounds__(256)
void gather_kernel(const float* __restrict__ X, const float* __restrict__ Q,
                   const float* __restrict__ Kin, const float* __restrict__ Ctot,
                   const float* __restrict__ Pre2, float* __restrict__ out)
{
    const int bx   = blockIdx.x;
    const int q    = ((bx & 7) << 10) | (bx >> 3);   // XCD-contiguous q ranges
    const int m    = threadIdx.x >> 6;
    const int lane = threadIdx.x & 63;

    const float t1 = X[(size_t)q * DD + DD - 1];
    const float qv = Q[(size_t)q * DD + lane];
    const float* Xm = X + (size_t)m * TT * DD;

    // ---- ballot k-ary search: count = #{ j : t2[j] <= t1 } ----
    int base;
    {   // round 1: stride 128, probes cover the whole array
        int p = lane * 128 + 127;
        float v = Xm[(size_t)p * DD + DD - 1];
        base = __popcll(__ballot(v <= t1)) * 128;     // count in [base, base+128) or ==8192
    }
    {   // round 2: stride 2
        int p = base + lane * 2 + 1;
        int pa = min(p, TT - 1);
        float v = Xm[(size_t)pa * DD + DD - 1];
        bool ok = (p < TT) && (v <= t1);
        base += __popcll(__ballot(ok)) * 2;           // count in [base, base+2)
    }
    {   // round 3: stride 1 (exact; lanes past count-1 read > t1 by sortedness)
        int p = base + lane;
        int pa = min(p, TT - 1);
        float v = Xm[(size_t)pa * DD + DD - 1];
        bool ok = (p < TT) && (v <= t1);
        base += __popcll(__ballot(ok));               // == count
    }
    const int id = base - 1;

    float a0 = 0.f, a1 = 0.f;
    if (id >= 0) {
        const int cg = id >> 5;                       // chunk 0..255
        const int g  = id >> 8;                       // group 0..31
        const float* P = Pre2 + ((size_t)(m * NG + g) << 7);
        float s0 = P[lane], s1 = P[64 + lane];
        for (int c = g * 8; c < cg; ++c) {            // <=7 group-local chunks
            const float* Cr = Ctot + ((size_t)(m * NCH + c) << 7);
            s0 += Cr[lane]; s1 += Cr[64 + lane];
        }
        const float* Kb = Kin + ((size_t)m * TT + (size_t)cg * CH) * DD;
        const float* Vb = Xm  + (size_t)cg * CH * DD;
        const int n = id - cg * CH;                   // 0..31, wave-uniform
        #pragma unroll 4
        for (int tt = 0; tt <= n; ++tt) {
            float kv = Kb[tt * DD + lane];
            float2 vv = *(const float2*)(Vb + tt * DD);
            s0 = fmaf(kv, vv.x, s0);
            s1 = fmaf(kv, vv.y, s1);
        }
        a0 = qv * s0;
        a1 = qv * s1;
    }
    #pragma unroll
    for (int off = 32; off > 0; off >>= 1) {
        a0 += __shfl_xor(a0, off, 64);
        a1 += __shfl_xor(a1, off, 64);
    }
    __shared__ float red[MODS][2];
    if (lane == 0) { red[m][0] = a0; red[m][1] = a1; }
    __syncthreads();
    if (threadIdx.x == 0) {
        out[(q << 1)]     = red[0][0] + red[1][0] + red[2][0] + red[3][0];
        out[(q << 1) + 1] = red[0][1] + red[1][1] + red[2][1] + red[3][1];
    }
}

extern "C" void kernel_launch(void* const* d_in, const int* in_sizes, int n_in,
                              void* d_out, int out_size, void* d_ws, size_t ws_size,
                              hipStream_t stream)
{
    const float* X    = (const float*)d_in[0];
    const float* wq_w = (const float*)d_in[1];
    const float* wq_b = (const float*)d_in[2];
    const float* wk_w = (const float*)d_in[3];
    const float* wk_b = (const float*)d_in[4];
    float* out = (float*)d_out;

    float* ws   = (float*)d_ws;
    float* Q    = ws;                                   // TT*DD             (2 MB)
    float* K    = Q    + (size_t)TT * DD;               // MODS*TT*DD        (8 MB)
    float* Ctot = K    + (size_t)MODS * TT * DD;        // MODS*NCH*128      (512 KB)
    float* Pre2 = Ctot + (size_t)MODS * NCH * 128;      // MODS*NG*128       (64 KB)

    mlp_kernel   <<<dim3(TT/64, 5),  256, 0, stream>>>(X, wq_w, wq_b, wk_w, wk_b, Q, K);
    scan_partial <<<dim3(NCH, MODS), 128, 0, stream>>>(K, X, Ctot);
    g2_prefix    <<<MODS,            256, 0, stream>>>(Ctot, Pre2);
    gather_kernel<<<TT,              256, 0, stream>>>(X, Q, K, Ctot, Pre2, out);
}

// Round 6
// 131.644 us; speedup vs baseline: 1.1262x; 1.1262x over previous
//
#include <hip/hip_runtime.h>

#define TT 8192
#define DD 64
#define MODS 4
#define NCH 256
#define CH  32    // TT / NCH
#define NG  32    // chunk groups (8 chunks each)

typedef __attribute__((ext_vector_type(8))) short bf16x8;
typedef __attribute__((ext_vector_type(4))) float f32x4;

// round-to-nearest-even fp32 -> bf16 bits
__device__ __forceinline__ unsigned f2bf1(float x) {
    unsigned u = __float_as_uint(x);
    return (u + 0x7FFFu + ((u >> 16) & 1u)) >> 16;
}
__device__ __forceinline__ unsigned packbf(float a, float b) {
    return f2bf1(a) | (f2bf1(b) << 16);
}

// stage one fp32 W layer [d][c] -> LDS bf16 W^T [c][d] (pitch 72 shorts).
__device__ __forceinline__ void stage_w(const float* __restrict__ Wl,
                                        unsigned short* wb, int c, int dp0)
{
    #pragma unroll
    for (int it = 0; it < 8; ++it) {
        int dp = dp0 + 4 * it;                    // 0..31 (pair of d's)
        float w0 = Wl[(2 * dp)     * DD + c];
        float w1 = Wl[(2 * dp + 1) * DD + c];
        *(unsigned*)&wb[c * 72 + 2 * dp] = packbf(w0, w1);
    }
}

// ---------------------------------------------------------------------------
// Kernel 1: the 5 MLPs via bf16 MFMA, y^T = W^T x^T per layer.
// (unchanged from round 5 — W staged once/block, double-buffered; x per-wave.)
// ---------------------------------------------------------------------------
__global__ __launch_bounds__(256)
void mlp_kernel(const float* __restrict__ X,
                const float* __restrict__ wq_w, const float* __restrict__ wq_b,
                const float* __restrict__ wk_w, const float* __restrict__ wk_b,
                float* __restrict__ Q, float* __restrict__ Kout)
{
    __shared__ unsigned short xbuf[4][16][72];   //  9,216 B
    __shared__ unsigned short wbuf[2][64][72];   // 18,432 B

    const int job = blockIdx.y;
    const float *xin, *Wj, *Bias;
    float* out;
    if (job == 0) { xin = X; Wj = wq_w; Bias = wq_b; out = Q; }
    else {
        const int m = job - 1;
        xin  = X    + (size_t)m * TT * DD;
        Wj   = wk_w + (size_t)m * 3 * DD * DD;
        Bias = wk_b + (size_t)m * 3 * DD;
        out  = Kout + (size_t)m * TT * DD;
    }

    const int t    = threadIdx.x;
    const int wv   = t >> 6;
    const int lane = t & 63;
    const int quad = lane >> 4;
    const int l15  = lane & 15;
    const int row0 = blockIdx.x * 64 + wv * 16;
    unsigned short* xb = &xbuf[wv][0][0];
    const int wc = t & 63, wdp0 = t >> 6;

    {
        const float4* src = (const float4*)(xin + (size_t)row0 * DD);
        #pragma unroll
        for (int k = 0; k < 4; ++k) {
            int f = lane + 64 * k;
            int r = f >> 4, c4 = (f & 15) << 2;
            float4 v = src[f];
            uint2 p = make_uint2(packbf(v.x, v.y), packbf(v.z, v.w));
            *(uint2*)&xb[r * 72 + c4] = p;
        }
    }

    stage_w(Wj, &wbuf[0][0][0], wc, wdp0);

    #pragma unroll
    for (int l = 0; l < 3; ++l) {
        __syncthreads();
        const unsigned short* wb = &wbuf[l & 1][0][0];
        if (l < 2)
            stage_w(Wj + (size_t)(l + 1) * DD * DD, &wbuf[(l + 1) & 1][0][0], wc, wdp0);

        const float* Bl = Bias + l * DD;
        f32x4 acc[4];
        #pragma unroll
        for (int mt = 0; mt < 4; ++mt) {
            float4 b4 = *(const float4*)(Bl + 16 * mt + quad * 4);
            acc[mt][0] = b4.x; acc[mt][1] = b4.y; acc[mt][2] = b4.z; acc[mt][3] = b4.w;
        }

        bf16x8 xf[2];
        #pragma unroll
        for (int kt = 0; kt < 2; ++kt)
            xf[kt] = *(const bf16x8*)&xb[l15 * 72 + quad * 8 + kt * 32];

        #pragma unroll
        for (int mt = 0; mt < 4; ++mt) {
            #pragma unroll
            for (int kt = 0; kt < 2; ++kt) {
                bf16x8 wf = *(const bf16x8*)&wb[(16 * mt + l15) * 72 + quad * 8 + kt * 32];
                acc[mt] = __builtin_amdgcn_mfma_f32_16x16x32_bf16(wf, xf[kt], acc[mt], 0, 0, 0);
            }
        }

        if (l < 2) {
            #pragma unroll
            for (int mt = 0; mt < 4; ++mt) {
                float r0 = fmaxf(acc[mt][0], 0.f), r1 = fmaxf(acc[mt][1], 0.f);
                float r2 = fmaxf(acc[mt][2], 0.f), r3 = fmaxf(acc[mt][3], 0.f);
                uint2 p = make_uint2(packbf(r0, r1), packbf(r2, r3));
                *(uint2*)&xb[l15 * 72 + 16 * mt + quad * 4] = p;
            }
        } else {
            #pragma unroll
            for (int mt = 0; mt < 4; ++mt) {
                float4 v = make_float4(acc[mt][0], acc[mt][1], acc[mt][2], acc[mt][3]);
                *(float4*)(out + (size_t)(row0 + l15) * DD + 16 * mt + quad * 4) = v;
            }
        }
    }
}

// ---------------------------------------------------------------------------
// Kernel 2: per-chunk partials + sub-chunk snapshots + dense time extract.
// grid = (NCH, MODS), block 128 (thread = e*64+d).
//   Ctot[m][c]       = sum over the chunk's 32 rows
//   Csub[m][c][j]    = sum over rows 0..8*(j+1)-1 (j=0..2; snapshot of the
//                      same serial FMA chain -> gather reconstruction is
//                      bit-identical to a straight serial scan)
//   times[m][t]      = X[m][t][63] (fp32, dense — feeds find_idx)
// ---------------------------------------------------------------------------
__global__ __launch_bounds__(128)
void scan_partial(const float* __restrict__ Kin, const float* __restrict__ X,
                  float* __restrict__ Ctot, float* __restrict__ Csub,
                  float* __restrict__ times)
{
    const int m = blockIdx.y, ch = blockIdx.x;
    const int tid = threadIdx.x;
    const int d = tid & 63, e = tid >> 6;
    const float* Kb = Kin + ((size_t)m * TT + (size_t)ch * CH) * DD;
    const float* Vb = X   + ((size_t)m * TT + (size_t)ch * CH) * DD;

    if (tid < CH)
        times[(size_t)m * TT + (size_t)ch * CH + tid] = Vb[tid * DD + DD - 1];

    float acc = 0.f;
    #pragma unroll
    for (int j = 0; j < 4; ++j) {
        #pragma unroll
        for (int s = 0; s < 8; ++s) {
            int tt = j * 8 + s;
            acc = fmaf(Kb[tt * DD + d], Vb[tt * DD + e], acc);
        }
        if (j < 3)
            Csub[(((size_t)m * NCH + ch) * 3 + j) * 128 + tid] = acc;
    }
    Ctot[((size_t)m * NCH + ch) * 128 + tid] = acc;
}

// ---------------------------------------------------------------------------
// Kernel 3: exclusive prefix over 32 groups of 8 chunks (unchanged).
// ---------------------------------------------------------------------------
__global__ __launch_bounds__(256)
void g2_prefix(const float* __restrict__ Ctot, float* __restrict__ Pre2)
{
    __shared__ float pp[NG][128];
    const int m = blockIdx.x;
    const int sub = threadIdx.x >> 7, t = threadIdx.x & 127;
    const int g0 = sub * 16;
    float acc = 0.f;
    for (int g = g0; g < g0 + 16; ++g) {
        float s = 0.f;
        #pragma unroll
        for (int i = 0; i < 8; ++i)
            s += Ctot[(size_t)(m * NCH + g * 8 + i) * 128 + t];
        acc += s;
        pp[g][t] = acc;
    }
    __syncthreads();
    for (int g = g0; g < g0 + 16; ++g) {
        float e = (g == 0) ? 0.f
                : (g <= 16) ? pp[g - 1][t]
                            : pp[15][t] + pp[g - 1][t];
        Pre2[(size_t)(m * NG + g) * 128 + t] = e;
    }
}

// ---------------------------------------------------------------------------
// Kernel 4: find_idx — per-(q,m) binary search over the DENSE times array
// (32 KB per modality, L1/L2-resident). Consecutive lanes = consecutive q
// -> probes share lines after the first few rounds. 128 blocks x 256 thr.
// ---------------------------------------------------------------------------
__global__ __launch_bounds__(256)
void find_idx(const float* __restrict__ times, int* __restrict__ idx)
{
    const int b = blockIdx.x;                 // 0..127
    const int m = b >> 5;                     // 0..3
    const int q = ((b & 31) << 8) + threadIdx.x;
    const float t1 = times[q];                // modality 0 row IS the t1 array
    const float* t2 = times + (size_t)m * TT;
    int lo = 0, hi = TT;
    #pragma unroll 1
    for (int s = 0; s < 13; ++s) {            // 2^13 == TT
        int mid = (lo + hi) >> 1;
        bool le = (t2[mid] <= t1);
        lo = le ? mid + 1 : lo;
        hi = le ? hi : mid;
    }
    idx[(size_t)m * TT + q] = lo - 1;         // searchsorted(right) - 1
}

// ---------------------------------------------------------------------------
// Kernel 5: gather. One wave per (query, modality); NO search — reads idx.
// Base = Pre2[group] + <=7 Ctot rows + Csub sub-chunk + <=8-row recompute.
// XCD swizzle keeps q-contiguous (monotone idx -> hot K/Ctot lines per XCD).
// ---------------------------------------------------------------------------
__global__ __launch_bounds__(256)
void gather_kernel(const float* __restrict__ X, const float* __restrict__ Q,
                   const float* __restrict__ Kin, const float* __restrict__ Ctot,
                   const float* __restrict__ Csub, const float* __restrict__ Pre2,
                   const int* __restrict__ idx, float* __restrict__ out)
{
    const int bx   = blockIdx.x;
    const int q    = ((bx & 7) << 10) | (bx >> 3);   // XCD-contiguous q ranges
    const int m    = threadIdx.x >> 6;
    const int lane = threadIdx.x & 63;

    const float qv = Q[(size_t)q * DD + lane];
    const int id = idx[(size_t)m * TT + q];

    float a0 = 0.f, a1 = 0.f;
    if (id >= 0) {
        const int cg = id >> 5;                       // chunk 0..255
        const int g  = id >> 8;                       // group 0..31
        const float* P = Pre2 + ((size_t)(m * NG + g) << 7);
        float s0 = P[lane], s1 = P[64 + lane];
        for (int c = g * 8; c < cg; ++c) {            // <=7 group-local chunks
            const float* Cr = Ctot + ((size_t)(m * NCH + c) << 7);
            s0 += Cr[lane]; s1 += Cr[64 + lane];
        }
        const int n = id - cg * CH;                   // 0..31, wave-uniform
        const int j = n >> 3;                         // sub-chunk 0..3
        if (j > 0) {
            const float* Sr = Csub + (((size_t)m * NCH + cg) * 3 + (j - 1)) * 128;
            s0 += Sr[lane]; s1 += Sr[64 + lane];
        }
        const float* Kb = Kin + ((size_t)m * TT + (size_t)cg * CH) * DD;
        const float* Vb = X   + ((size_t)m * TT + (size_t)cg * CH) * DD;
        #pragma unroll 1
        for (int tt = j * 8; tt <= n; ++tt) {         // <=8 rows (avg ~4.5)
            float kv = Kb[tt * DD + lane];
            float2 vv = *(const float2*)(Vb + tt * DD);
            s0 = fmaf(kv, vv.x, s0);
            s1 = fmaf(kv, vv.y, s1);
        }
        a0 = qv * s0;
        a1 = qv * s1;
    }
    #pragma unroll
    for (int off = 32; off > 0; off >>= 1) {
        a0 += __shfl_xor(a0, off, 64);
        a1 += __shfl_xor(a1, off, 64);
    }
    __shared__ float red[MODS][2];
    if (lane == 0) { red[m][0] = a0; red[m][1] = a1; }
    __syncthreads();
    if (threadIdx.x == 0) {
        out[(q << 1)]     = red[0][0] + red[1][0] + red[2][0] + red[3][0];
        out[(q << 1) + 1] = red[0][1] + red[1][1] + red[2][1] + red[3][1];
    }
}

extern "C" void kernel_launch(void* const* d_in, const int* in_sizes, int n_in,
                              void* d_out, int out_size, void* d_ws, size_t ws_size,
                              hipStream_t stream)
{
    const float* X    = (const float*)d_in[0];
    const float* wq_w = (const float*)d_in[1];
    const float* wq_b = (const float*)d_in[2];
    const float* wk_w = (const float*)d_in[3];
    const float* wk_b = (const float*)d_in[4];
    float* out = (float*)d_out;

    float* ws    = (float*)d_ws;
    float* Q     = ws;                                   // TT*DD             (2 MB)
    float* K     = Q     + (size_t)TT * DD;              // MODS*TT*DD        (8 MB)
    float* Ctot  = K     + (size_t)MODS * TT * DD;       // MODS*NCH*128      (512 KB)
    float* Pre2  = Ctot  + (size_t)MODS * NCH * 128;     // MODS*NG*128       (64 KB)
    float* Csub  = Pre2  + (size_t)MODS * NG * 128;      // MODS*NCH*3*128    (1.5 MB)
    float* times = Csub  + (size_t)MODS * NCH * 3 * 128; // MODS*TT           (128 KB)
    int*   idx   = (int*)(times + (size_t)MODS * TT);    // MODS*TT           (128 KB)

    mlp_kernel   <<<dim3(TT/64, 5),  256, 0, stream>>>(X, wq_w, wq_b, wk_w, wk_b, Q, K);
    scan_partial <<<dim3(NCH, MODS), 128, 0, stream>>>(K, X, Ctot, Csub, times);
    g2_prefix    <<<MODS,            256, 0, stream>>>(Ctot, Pre2);
    find_idx     <<<128,             256, 0, stream>>>(times, idx);
    gather_kernel<<<TT,              256, 0, stream>>>(X, Q, K, Ctot, Csub, Pre2, idx, out);
}